// Round 2
// baseline (467.006 us; speedup 1.0000x reference)
//
#include <hip/hip_runtime.h>

#define N 8192
#define DIN 128
#define DH 48
#define MT 128           // rows per k_gat block
#define KC 64            // j-chunk
#define PSTR (KC + 8)    // f16 row stride: 144 B -> 2-way bank aliasing (free)
#define NSPLIT 8
#define JSPAN (N / NSPLIT)   // 1024
#define NCHUNK (JSPAN / KC)  // 16
#define ACC_STRIDE 64    // 48 dims + lsum@48 + 15 unused (MFMA N-tile padding)
#define RB 32            // rows per k_mlp block

typedef _Float16 half8 __attribute__((ext_vector_type(8)));
typedef float f32x4 __attribute__((ext_vector_type(4)));

// ---------------- Kernel 1a: Wh = x @ Wgat^T  [8192,128]x[48,128] -> [8192,48]
__global__ __launch_bounds__(256) void k_wh(const float* __restrict__ x,
                                            const float* __restrict__ Wg,
                                            float* __restrict__ Wh) {
    __shared__ float wT[DIN * DH];  // transposed: wT[k*DH + c] = Wg[c*DIN + k]
    int t = threadIdx.x;
    for (int e = t; e < DIN * DH; e += 256) {
        int c = e / DIN, k = e % DIN;
        wT[k * DH + c] = Wg[e];
    }
    __syncthreads();
    int o = blockIdx.x * 256 + t;      // o < 8192*48
    int r = o / DH, c = o % DH;
    const float4* xr = (const float4*)(x + (size_t)r * DIN);
    float acc = 0.f;
    #pragma unroll 8
    for (int k4 = 0; k4 < DIN / 4; ++k4) {
        float4 xv = xr[k4];
        int kb = k4 * 4;
        acc += xv.x * wT[(kb + 0) * DH + c];
        acc += xv.y * wT[(kb + 1) * DH + c];
        acc += xv.z * wT[(kb + 2) * DH + c];
        acc += xv.w * wT[(kb + 3) * DH + c];
    }
    Wh[o] = acc;
}

// ---------------- Kernel 1b: s = Wh @ a^T
__global__ __launch_bounds__(256) void k_s(const float* __restrict__ Wh,
                                           const float* __restrict__ a,
                                           float* __restrict__ s) {
    int r = blockIdx.x * 256 + threadIdx.x;
    const float4* wr = (const float4*)(Wh + (size_t)r * DH);
    const float4* av = (const float4*)a;
    float acc = 0.f;
    #pragma unroll
    for (int k4 = 0; k4 < DH / 4; ++k4) {
        float4 w = wr[k4]; float4 aa = av[k4];
        acc += w.x * aa.x + w.y * aa.y + w.z * aa.z + w.w * aa.w;
    }
    s[r] = acc;
}

// ---------------- Kernel 2: fused masked-softmax attention, f16-MFMA MAC.
// MT=128 rows/block (LDS 28 KB -> multiple blocks/CU). T14 register prefetch:
// next chunk's adj (16x int2) + Wh (12x f32) issued right after current
// consume; loads stay in flight across the barriers + MFMA phase (register
// loads are NOT drained by __syncthreads, unlike global_load_lds).
__global__ __launch_bounds__(256) void k_gat(const int* __restrict__ adj,
                                             const float* __restrict__ Wh,
                                             const float* __restrict__ s,
                                             float* __restrict__ accWs) {
    __shared__ _Float16 pS[MT][PSTR];   // A: P[row][j]
    __shared__ _Float16 wS[64][PSTR];   // B^T: wS[d][j]; d=48 ones, 49..63 zero
    __shared__ float sRow[MT];
    int t = threadIdx.x;
    int tile = blockIdx.x & 63;        // 64 row tiles of 128
    int split = blockIdx.x >> 6;       // 0..7
    int i0 = tile * MT;
    int jbase = split * JSPAN;

    int lane = t & 63, w = t >> 6;
    int ln16 = lane & 15, kq = lane >> 4;   // MFMA lane decomposition
    int jp = t & 31, rg = t >> 5;           // phase A: j-pair, row group

    const int* adjBase = adj + (size_t)(i0 + rg * 16) * N + jbase + 2 * jp;

    // ---- prologue: issue chunk-0 prefetch into registers
    int2 adjR[16];
    float whR[12];
    #pragma unroll
    for (int it = 0; it < 16; ++it)
        adjR[it] = *(const int2*)(adjBase + (size_t)it * N);
    #pragma unroll
    for (int k = 0; k < 12; ++k)
        whR[k] = Wh[(size_t)jbase * DH + t + k * 256];

    if (t < MT) sRow[t] = s[i0 + t];
    // init constant B rows (ones col @48, zeros 49..63), incl pad
    for (int e = t; e < 16 * PSTR; e += 256) {
        int n = 48 + e / PSTR, k = e % PSTR;
        wS[n][k] = (n == 48) ? (_Float16)1.0f : (_Float16)0.0f;
    }

    f32x4 acc[2][4];
    #pragma unroll
    for (int a0 = 0; a0 < 2; ++a0)
        #pragma unroll
        for (int b0 = 0; b0 < 4; ++b0) acc[a0][b0] = (f32x4){0.f, 0.f, 0.f, 0.f};

    __syncthreads();

    for (int chunk = 0; chunk < NCHUNK; ++chunk) {
        int j0 = jbase + chunk * KC;
        // ---- write wS from prefetched whR (f32 -> f16)
        #pragma unroll
        for (int k = 0; k < 12; ++k) {
            int e = t + k * 256;            // e < 3072 = 64*48
            int jc = e / DH, d = e % DH;
            wS[d][jc] = (_Float16)whR[k];
        }
        // ---- phase A: p (f16) for 128 rows x 64 j from prefetched adjR
        {
            float2 sj = *(const float2*)(s + j0 + 2 * jp);
            #pragma unroll
            for (int it = 0; it < 16; ++it) {
                int r = rg * 16 + it;
                int2 av = adjR[it];
                float e0 = sRow[r] + sj.x;
                float e1 = sRow[r] + sj.y;
                e0 = fmaxf(e0, 0.2f * e0);              // LeakyReLU(0.2)
                e1 = fmaxf(e1, 0.2f * e1);
                float p0 = av.x ? __expf(e0) : 0.f;     // masked -> exact 0
                float p1 = av.y ? __expf(e1) : 0.f;
                union { _Float16 h[2]; unsigned u; } pk;
                pk.h[0] = (_Float16)p0;                 // RTN
                pk.h[1] = (_Float16)p1;
                *(unsigned*)&pS[r][2 * jp] = pk.u;
            }
        }
        // ---- issue next-chunk prefetch (in flight across barriers + MFMA)
        if (chunk < NCHUNK - 1) {
            int jn = j0 + KC;
            #pragma unroll
            for (int it = 0; it < 16; ++it)
                adjR[it] = *(const int2*)(adjBase + (size_t)it * N + (chunk + 1) * KC);
            #pragma unroll
            for (int k = 0; k < 12; ++k)
                whR[k] = Wh[(size_t)jn * DH + t + k * 256];
        }
        __syncthreads();
        // ---- MFMA MAC: wave w owns M-tiles w*2..w*2+1, all 4 N-tiles
        {
            const int m0 = w * 32;
            #pragma unroll
            for (int kt = 0; kt < 2; ++kt) {
                const int kk = kt * 32 + kq * 8;
                half8 b[4];
                #pragma unroll
                for (int nt = 0; nt < 4; ++nt)
                    b[nt] = *(const half8*)&wS[nt * 16 + ln16][kk];
                #pragma unroll
                for (int mtl = 0; mtl < 2; ++mtl) {
                    half8 a = *(const half8*)&pS[m0 + mtl * 16 + ln16][kk];
                    #pragma unroll
                    for (int nt = 0; nt < 4; ++nt)
                        acc[mtl][nt] = __builtin_amdgcn_mfma_f32_16x16x32_f16(
                            a, b[nt], acc[mtl][nt], 0, 0, 0);
                }
            }
        }
        __syncthreads();
    }
    // ---- epilogue: C/D layout col=lane&15, row=kq*4+reg
    size_t rbase = (size_t)split * N + i0;
    #pragma unroll
    for (int mtl = 0; mtl < 2; ++mtl) {
        #pragma unroll
        for (int nt = 0; nt < 4; ++nt) {
            int col = nt * 16 + ln16;
            if (nt == 3 && ln16 != 0) continue;   // only col 48 (lsum) useful
            #pragma unroll
            for (int reg = 0; reg < 4; ++reg) {
                int row = w * 32 + mtl * 16 + kq * 4 + reg;
                accWs[(rbase + row) * ACC_STRIDE + col] = acc[mtl][nt][reg];
            }
        }
    }
}

// ---------------- Kernel 3: reduce splits + LayerNorm + MFMA MLP 48->256->128->32
// MLP1/MLP2 on the matrix pipe (f16 inputs, f32 accum); W1/W2 fragments are
// f16-converted straight from global (L2-hot, 128 KB). hN/h1 strides padded
// (72/264 f16) to avoid the stride-128B 16-way LDS bank conflict on ds_read_b128.
__global__ __launch_bounds__(256) void k_mlp(const float* __restrict__ accWs,
                                             const float* __restrict__ gamma,
                                             const float* __restrict__ beta,
                                             const float* __restrict__ W1, const float* __restrict__ b1,
                                             const float* __restrict__ W2, const float* __restrict__ b2,
                                             const float* __restrict__ W3, const float* __restrict__ b3,
                                             float* __restrict__ out) {
    __shared__ float hacc[RB * 49];
    __shared__ _Float16 hN[RB * 72];    // [32][72] f16, cols 48..71 zero (K pad)
    __shared__ _Float16 h1[RB * 264];   // [32][264] f16
    __shared__ float h2[RB * 132];      // [32][132] f32
    int t = threadIdx.x;
    int r0 = blockIdx.x * RB;
    int lane = t & 63, w = t >> 6;
    int ln16 = lane & 15, kq = lane >> 4;

    // reduce K-split partials (d: 0..47 dims, 48 = lsum)
    for (int e = t; e < RB * 49; e += 256) {
        int r = e / 49, d = e % 49;
        size_t base = (size_t)(r0 + r) * ACC_STRIDE + d;
        float v = 0.f;
        #pragma unroll
        for (int sp = 0; sp < NSPLIT; ++sp)
            v += accWs[(size_t)sp * N * ACC_STRIDE + base];
        hacc[e] = v;
    }
    __syncthreads();

    // LayerNorm (two-pass), h' = acc / l ; store f16 for MFMA A-operand
    if (t < RB) {
        float invl = 1.f / hacc[t * 49 + 48];
        float sum = 0.f;
        for (int d = 0; d < DH; ++d) sum += hacc[t * 49 + d];
        float mean = sum * invl * (1.f / DH);
        float var = 0.f;
        for (int d = 0; d < DH; ++d) {
            float dv = hacc[t * 49 + d] * invl - mean;
            var += dv * dv;
        }
        var *= (1.f / DH);
        float rs = rsqrtf(var + 1e-5f);
        for (int d = 0; d < DH; ++d) {
            float hv = (hacc[t * 49 + d] * invl - mean) * rs;
            hN[t * 72 + d] = (_Float16)(hv * gamma[d] + beta[d]);
        }
        for (int d = DH; d < 72; ++d) hN[t * 72 + d] = (_Float16)0.f;
    }
    __syncthreads();

    // MLP1 (MFMA): M=32, N=256, K=48 padded to 64. wave w owns N-tiles w*4..w*4+3
    {
        f32x4 acc1[2][4];
        #pragma unroll
        for (int mt = 0; mt < 2; ++mt)
            #pragma unroll
            for (int nt = 0; nt < 4; ++nt) acc1[mt][nt] = (f32x4){0.f, 0.f, 0.f, 0.f};
        #pragma unroll
        for (int kt = 0; kt < 2; ++kt) {
            int k = kt * 32 + kq * 8;
            half8 a[2];
            #pragma unroll
            for (int mt = 0; mt < 2; ++mt)
                a[mt] = *(const half8*)&hN[(mt * 16 + ln16) * 72 + k];
            #pragma unroll
            for (int ntl = 0; ntl < 4; ++ntl) {
                int n = (w * 4 + ntl) * 16 + ln16;
                half8 b;
                #pragma unroll
                for (int i = 0; i < 8; ++i) b[i] = (_Float16)0.f;
                if (k < DH) {   // k in {0,8,16,24,32,40}; >=48 stays zero
                    float4 lo = *(const float4*)(W1 + n * DH + k);
                    float4 hi = *(const float4*)(W1 + n * DH + k + 4);
                    b[0] = (_Float16)lo.x; b[1] = (_Float16)lo.y;
                    b[2] = (_Float16)lo.z; b[3] = (_Float16)lo.w;
                    b[4] = (_Float16)hi.x; b[5] = (_Float16)hi.y;
                    b[6] = (_Float16)hi.z; b[7] = (_Float16)hi.w;
                }
                #pragma unroll
                for (int mt = 0; mt < 2; ++mt)
                    acc1[mt][ntl] = __builtin_amdgcn_mfma_f32_16x16x32_f16(
                        a[mt], b, acc1[mt][ntl], 0, 0, 0);
            }
        }
        #pragma unroll
        for (int mt = 0; mt < 2; ++mt)
            #pragma unroll
            for (int ntl = 0; ntl < 4; ++ntl) {
                int col = (w * 4 + ntl) * 16 + ln16;
                float bias = b1[col];
                #pragma unroll
                for (int reg = 0; reg < 4; ++reg) {
                    int row = mt * 16 + kq * 4 + reg;
                    float v = acc1[mt][ntl][reg] + bias;
                    h1[row * 264 + col] = (_Float16)fmaxf(v, 0.f);
                }
            }
    }
    __syncthreads();

    // MLP2 (MFMA): M=32, N=128, K=256. wave w owns N-tiles w*2, w*2+1
    {
        f32x4 acc2[2][2];
        #pragma unroll
        for (int mt = 0; mt < 2; ++mt)
            #pragma unroll
            for (int nt = 0; nt < 2; ++nt) acc2[mt][nt] = (f32x4){0.f, 0.f, 0.f, 0.f};
        #pragma unroll
        for (int kt = 0; kt < 8; ++kt) {
            int k = kt * 32 + kq * 8;
            half8 a[2];
            #pragma unroll
            for (int mt = 0; mt < 2; ++mt)
                a[mt] = *(const half8*)&h1[(mt * 16 + ln16) * 264 + k];
            #pragma unroll
            for (int ntl = 0; ntl < 2; ++ntl) {
                int n = (w * 2 + ntl) * 16 + ln16;
                float4 lo = *(const float4*)(W2 + n * 256 + k);
                float4 hi = *(const float4*)(W2 + n * 256 + k + 4);
                half8 b;
                b[0] = (_Float16)lo.x; b[1] = (_Float16)lo.y;
                b[2] = (_Float16)lo.z; b[3] = (_Float16)lo.w;
                b[4] = (_Float16)hi.x; b[5] = (_Float16)hi.y;
                b[6] = (_Float16)hi.z; b[7] = (_Float16)hi.w;
                #pragma unroll
                for (int mt = 0; mt < 2; ++mt)
                    acc2[mt][ntl] = __builtin_amdgcn_mfma_f32_16x16x32_f16(
                        a[mt], b, acc2[mt][ntl], 0, 0, 0);
            }
        }
        #pragma unroll
        for (int mt = 0; mt < 2; ++mt)
            #pragma unroll
            for (int ntl = 0; ntl < 2; ++ntl) {
                int col = (w * 2 + ntl) * 16 + ln16;
                float bias = b2[col];
                #pragma unroll
                for (int reg = 0; reg < 4; ++reg) {
                    int row = mt * 16 + kq * 4 + reg;
                    h2[row * 132 + col] = fmaxf(acc2[mt][ntl][reg] + bias, 0.f);
                }
            }
    }
    __syncthreads();

    // MLP3: 128 -> 32 (scalar; small)
    {
        int c = t & 31;
        int g = t >> 5;
        int rb = g * 4;
        float acc[4];
        float bias = b3[c];
        #pragma unroll
        for (int r = 0; r < 4; ++r) acc[r] = bias;
        const float4* wrow = (const float4*)(W3 + c * 128);
        for (int k4 = 0; k4 < 32; ++k4) {
            float4 wv = wrow[k4];
            #pragma unroll
            for (int r = 0; r < 4; ++r) {
                const float4 hv = *(const float4*)(&h2[(rb + r) * 132 + k4 * 4]);
                acc[r] += wv.x * hv.x + wv.y * hv.y + wv.z * hv.z + wv.w * hv.w;
            }
        }
        #pragma unroll
        for (int r = 0; r < 4; ++r)
            out[(size_t)(r0 + rb + r) * 32 + c] = acc[r];
    }
}

extern "C" void kernel_launch(void* const* d_in, const int* in_sizes, int n_in,
                              void* d_out, int out_size, void* d_ws, size_t ws_size,
                              hipStream_t stream) {
    const float* x     = (const float*)d_in[0];
    const int*   adj   = (const int*)d_in[1];
    const float* Wg    = (const float*)d_in[2];
    const float* a     = (const float*)d_in[3];
    const float* gamma = (const float*)d_in[4];
    const float* beta  = (const float*)d_in[5];
    const float* W1    = (const float*)d_in[6];
    const float* b1    = (const float*)d_in[7];
    const float* W2    = (const float*)d_in[8];
    const float* b2    = (const float*)d_in[9];
    const float* W3    = (const float*)d_in[10];
    const float* b3    = (const float*)d_in[11];
    float* out = (float*)d_out;

    float* ws = (float*)d_ws;
    float* Wh    = ws;                          // 8192*48
    float* s     = ws + (size_t)N * DH;         // 8192
    float* accWs = s + N;                       // NSPLIT*8192*64 = 16.8 MB

    k_wh<<<N * DH / 256, 256, 0, stream>>>(x, Wg, Wh);
    k_s<<<N / 256, 256, 0, stream>>>(Wh, a, s);
    k_gat<<<64 * NSPLIT, 256, 0, stream>>>(adj, Wh, s, accWs);
    k_mlp<<<N / RB, 256, 0, stream>>>(accWs, gamma, beta, W1, b1, W2, b2, W3, b3, out);
}

// Round 4
// 456.310 us; speedup vs baseline: 1.0234x; 1.0234x over previous
//
#include <hip/hip_runtime.h>

#define N 8192
#define DIN 128
#define DH 48
#define MT 128           // rows per k_gat block (4 waves x 32 rows)
#define KC 64            // j-chunk
#define PSTR (KC + 8)    // f16 row stride: 144 B -> 2-way bank aliasing (free)
#define NSPLIT 16
#define JSPAN (N / NSPLIT)   // 512
#define NCHUNK (JSPAN / KC)  // 8
#define ACC_STRIDE 64    // 48 dims + lsum@48 + 15 unused (MFMA N-tile padding)
#define RB 32            // rows per k_mlp block

typedef _Float16 half8 __attribute__((ext_vector_type(8)));
typedef float f32x4 __attribute__((ext_vector_type(4)));

// ---------------- Kernel 1a: Wh = x @ Wgat^T  [8192,128]x[48,128] -> [8192,48]
__global__ __launch_bounds__(256) void k_wh(const float* __restrict__ x,
                                            const float* __restrict__ Wg,
                                            float* __restrict__ Wh) {
    __shared__ float wT[DIN * DH];  // transposed: wT[k*DH + c] = Wg[c*DIN + k]
    int t = threadIdx.x;
    for (int e = t; e < DIN * DH; e += 256) {
        int c = e / DIN, k = e % DIN;
        wT[k * DH + c] = Wg[e];
    }
    __syncthreads();
    int o = blockIdx.x * 256 + t;      // o < 8192*48
    int r = o / DH, c = o % DH;
    const float4* xr = (const float4*)(x + (size_t)r * DIN);
    float acc = 0.f;
    #pragma unroll 8
    for (int k4 = 0; k4 < DIN / 4; ++k4) {
        float4 xv = xr[k4];
        int kb = k4 * 4;
        acc += xv.x * wT[(kb + 0) * DH + c];
        acc += xv.y * wT[(kb + 1) * DH + c];
        acc += xv.z * wT[(kb + 2) * DH + c];
        acc += xv.w * wT[(kb + 3) * DH + c];
    }
    Wh[o] = acc;
}

// ---------------- Kernel 1b: s = Wh @ a^T
__global__ __launch_bounds__(256) void k_s(const float* __restrict__ Wh,
                                           const float* __restrict__ a,
                                           float* __restrict__ s) {
    int r = blockIdx.x * 256 + threadIdx.x;
    const float4* wr = (const float4*)(Wh + (size_t)r * DH);
    const float4* av = (const float4*)a;
    float acc = 0.f;
    #pragma unroll
    for (int k4 = 0; k4 < DH / 4; ++k4) {
        float4 w = wr[k4]; float4 aa = av[k4];
        acc += w.x * aa.x + w.y * aa.y + w.z * aa.z + w.w * aa.w;
    }
    s[r] = acc;
}

// ---------------- Kernel 1c: WhT16[d][j], d in [0,64):
//   d<48 : (f16)Wh[j][d]   (same RTN cast as old wS staging)
//   d=48 : 1.0  (ones column -> lsum)          [R3 bugfix: these rows
//   d>48 : 0.0  (MFMA N-tile zero padding)      were missing -> OOB lsum]
__global__ __launch_bounds__(256) void k_tr(const float* __restrict__ Wh,
                                            _Float16* __restrict__ WhT16) {
    int o = blockIdx.x * 256 + threadIdx.x;   // o < 64*8192, d-major
    int d = o >> 13, j = o & 8191;
    _Float16 v;
    if (d < DH)       v = (_Float16)Wh[(size_t)j * DH + d];
    else if (d == DH) v = (_Float16)1.0f;
    else              v = (_Float16)0.0f;
    WhT16[o] = v;
}

// ---------------- Kernel 2: fused masked-softmax attention, BARRIER-FREE.
// Each wave owns 32 rows end-to-end: private pS slice (wave-internal LDS ->
// lgkmcnt only, NO s_barrier in the loop, so the adj register prefetch truly
// stays in flight across the MFMA phase -- __syncthreads would vmcnt(0)-drain
// it). B fragments load directly from f16 WhT16 (1 MB, L2-hot) as contiguous
// half8: B[k][n] = WhT16[n][j0+k..k+7]; rows 48..63 are the ones/zero pad.
__global__ __launch_bounds__(256, 3) void k_gat(const int* __restrict__ adj,
                                                const _Float16* __restrict__ WhT16,
                                                const float* __restrict__ s,
                                                float* __restrict__ accWs) {
    __shared__ _Float16 pS[MT][PSTR];   // A: P[row][j], per-wave 32-row slices
    __shared__ float sRow[MT];
    int t = threadIdx.x;
    int tile = blockIdx.x & 63;        // 64 row tiles of 128
    int split = blockIdx.x >> 6;       // 0..15
    int i0 = tile * MT;
    int jbase = split * JSPAN;

    int lane = t & 63, w = t >> 6;
    int ln16 = lane & 15, kq = lane >> 4;   // MFMA lane decomposition
    int jp = lane & 31, rh = lane >> 5;     // phase A: j-pair, row half

    int rw = w * 32;                        // wave's first row within tile
    const int* adjBase = adj + (size_t)(i0 + rw + rh * 16) * N + jbase + 2 * jp;

    // per-wave sRow staging (same-wave DS is in-order; lgkmcnt covers it)
    if (lane < 32) sRow[rw + lane] = s[i0 + rw + lane];

    // ---- prologue: chunk-0 adj prefetch into registers
    int2 adjR[16];
    #pragma unroll
    for (int it = 0; it < 16; ++it)
        adjR[it] = *(const int2*)(adjBase + (size_t)it * N);

    f32x4 acc[2][4];
    #pragma unroll
    for (int a0 = 0; a0 < 2; ++a0)
        #pragma unroll
        for (int b0 = 0; b0 < 4; ++b0) acc[a0][b0] = (f32x4){0.f, 0.f, 0.f, 0.f};

    for (int chunk = 0; chunk < NCHUNK; ++chunk) {
        int j0 = jbase + chunk * KC;
        // ---- B fragments for this chunk (issued first: oldest vmcnt slots,
        //      so waiting on them at MFMA leaves the adj prefetch in flight)
        half8 bf[2][4];
        #pragma unroll
        for (int kt = 0; kt < 2; ++kt)
            #pragma unroll
            for (int nt = 0; nt < 4; ++nt)
                bf[kt][nt] = *(const half8*)&WhT16[(size_t)(nt * 16 + ln16) * N
                                                  + j0 + kt * 32 + kq * 8];
        // ---- phase A: p (f16) for wave's 32 rows x 64 j from prefetched adjR
        {
            float2 sj = *(const float2*)(s + j0 + 2 * jp);
            #pragma unroll
            for (int it = 0; it < 16; ++it) {
                int r = rw + rh * 16 + it;
                int2 av = adjR[it];
                float e0 = sRow[r] + sj.x;
                float e1 = sRow[r] + sj.y;
                e0 = fmaxf(e0, 0.2f * e0);              // LeakyReLU(0.2)
                e1 = fmaxf(e1, 0.2f * e1);
                float p0 = av.x ? __expf(e0) : 0.f;     // masked -> exact 0
                float p1 = av.y ? __expf(e1) : 0.f;
                union { _Float16 h[2]; unsigned u; } pk;
                pk.h[0] = (_Float16)p0;                 // RTN
                pk.h[1] = (_Float16)p1;
                *(unsigned*)&pS[r][2 * jp] = pk.u;
            }
        }
        // ---- issue next-chunk adj prefetch (no barrier ahead -> stays in flight)
        if (chunk < NCHUNK - 1) {
            #pragma unroll
            for (int it = 0; it < 16; ++it)
                adjR[it] = *(const int2*)(adjBase + (size_t)it * N + (chunk + 1) * KC);
        }
        // ---- MFMA MAC (wave-internal pS: compiler inserts lgkmcnt, no barrier)
        #pragma unroll
        for (int kt = 0; kt < 2; ++kt) {
            const int kk = kt * 32 + kq * 8;
            #pragma unroll
            for (int mtl = 0; mtl < 2; ++mtl) {
                half8 a = *(const half8*)&pS[rw + mtl * 16 + ln16][kk];
                #pragma unroll
                for (int nt = 0; nt < 4; ++nt)
                    acc[mtl][nt] = __builtin_amdgcn_mfma_f32_16x16x32_f16(
                        a, bf[kt][nt], acc[mtl][nt], 0, 0, 0);
            }
        }
    }
    // ---- epilogue: C/D layout col=lane&15, row=kq*4+reg
    size_t rbase = (size_t)split * N + i0;
    #pragma unroll
    for (int mtl = 0; mtl < 2; ++mtl) {
        #pragma unroll
        for (int nt = 0; nt < 4; ++nt) {
            int col = nt * 16 + ln16;
            if (nt == 3 && ln16 != 0) continue;   // only col 48 (lsum) useful
            #pragma unroll
            for (int reg = 0; reg < 4; ++reg) {
                int row = rw + mtl * 16 + kq * 4 + reg;
                accWs[(rbase + row) * ACC_STRIDE + col] = acc[mtl][nt][reg];
            }
        }
    }
}

// ---------------- Kernel 3: reduce splits + LayerNorm + MFMA MLP 48->256->128->32
__global__ __launch_bounds__(256) void k_mlp(const float* __restrict__ accWs,
                                             const float* __restrict__ gamma,
                                             const float* __restrict__ beta,
                                             const float* __restrict__ W1, const float* __restrict__ b1,
                                             const float* __restrict__ W2, const float* __restrict__ b2,
                                             const float* __restrict__ W3, const float* __restrict__ b3,
                                             float* __restrict__ out) {
    __shared__ float hacc[RB * 49];
    __shared__ _Float16 hN[RB * 72];    // [32][72] f16, cols 48..71 zero (K pad)
    __shared__ _Float16 h1[RB * 264];   // [32][264] f16
    __shared__ float h2[RB * 132];      // [32][132] f32
    int t = threadIdx.x;
    int r0 = blockIdx.x * RB;
    int lane = t & 63, w = t >> 6;
    int ln16 = lane & 15, kq = lane >> 4;

    // reduce K-split partials (d: 0..47 dims, 48 = lsum)
    for (int e = t; e < RB * 49; e += 256) {
        int r = e / 49, d = e % 49;
        size_t base = (size_t)(r0 + r) * ACC_STRIDE + d;
        float v = 0.f;
        #pragma unroll
        for (int sp = 0; sp < NSPLIT; ++sp)
            v += accWs[(size_t)sp * N * ACC_STRIDE + base];
        hacc[e] = v;
    }
    __syncthreads();

    // LayerNorm (two-pass), h' = acc / l ; store f16 for MFMA A-operand
    if (t < RB) {
        float invl = 1.f / hacc[t * 49 + 48];
        float sum = 0.f;
        for (int d = 0; d < DH; ++d) sum += hacc[t * 49 + d];
        float mean = sum * invl * (1.f / DH);
        float var = 0.f;
        for (int d = 0; d < DH; ++d) {
            float dv = hacc[t * 49 + d] * invl - mean;
            var += dv * dv;
        }
        var *= (1.f / DH);
        float rs = rsqrtf(var + 1e-5f);
        for (int d = 0; d < DH; ++d) {
            float hv = (hacc[t * 49 + d] * invl - mean) * rs;
            hN[t * 72 + d] = (_Float16)(hv * gamma[d] + beta[d]);
        }
        for (int d = DH; d < 72; ++d) hN[t * 72 + d] = (_Float16)0.f;
    }
    __syncthreads();

    // MLP1 (MFMA): M=32, N=256, K=48 padded to 64. wave w owns N-tiles w*4..w*4+3
    {
        f32x4 acc1[2][4];
        #pragma unroll
        for (int mt = 0; mt < 2; ++mt)
            #pragma unroll
            for (int nt = 0; nt < 4; ++nt) acc1[mt][nt] = (f32x4){0.f, 0.f, 0.f, 0.f};
        #pragma unroll
        for (int kt = 0; kt < 2; ++kt) {
            int k = kt * 32 + kq * 8;
            half8 a[2];
            #pragma unroll
            for (int mt = 0; mt < 2; ++mt)
                a[mt] = *(const half8*)&hN[(mt * 16 + ln16) * 72 + k];
            #pragma unroll
            for (int ntl = 0; ntl < 4; ++ntl) {
                int n = (w * 4 + ntl) * 16 + ln16;
                half8 b;
                #pragma unroll
                for (int i = 0; i < 8; ++i) b[i] = (_Float16)0.f;
                if (k < DH) {   // k in {0,8,16,24,32,40}; >=48 stays zero
                    float4 lo = *(const float4*)(W1 + n * DH + k);
                    float4 hi = *(const float4*)(W1 + n * DH + k + 4);
                    b[0] = (_Float16)lo.x; b[1] = (_Float16)lo.y;
                    b[2] = (_Float16)lo.z; b[3] = (_Float16)lo.w;
                    b[4] = (_Float16)hi.x; b[5] = (_Float16)hi.y;
                    b[6] = (_Float16)hi.z; b[7] = (_Float16)hi.w;
                }
                #pragma unroll
                for (int mt = 0; mt < 2; ++mt)
                    acc1[mt][ntl] = __builtin_amdgcn_mfma_f32_16x16x32_f16(
                        a[mt], b, acc1[mt][ntl], 0, 0, 0);
            }
        }
        #pragma unroll
        for (int mt = 0; mt < 2; ++mt)
            #pragma unroll
            for (int ntl = 0; ntl < 4; ++ntl) {
                int col = (w * 4 + ntl) * 16 + ln16;
                float bias = b1[col];
                #pragma unroll
                for (int reg = 0; reg < 4; ++reg) {
                    int row = mt * 16 + kq * 4 + reg;
                    float v = acc1[mt][ntl][reg] + bias;
                    h1[row * 264 + col] = (_Float16)fmaxf(v, 0.f);
                }
            }
    }
    __syncthreads();

    // MLP2 (MFMA): M=32, N=128, K=256. wave w owns N-tiles w*2, w*2+1
    {
        f32x4 acc2[2][2];
        #pragma unroll
        for (int mt = 0; mt < 2; ++mt)
            #pragma unroll
            for (int nt = 0; nt < 2; ++nt) acc2[mt][nt] = (f32x4){0.f, 0.f, 0.f, 0.f};
        #pragma unroll
        for (int kt = 0; kt < 8; ++kt) {
            int k = kt * 32 + kq * 8;
            half8 a[2];
            #pragma unroll
            for (int mt = 0; mt < 2; ++mt)
                a[mt] = *(const half8*)&h1[(mt * 16 + ln16) * 264 + k];
            #pragma unroll
            for (int ntl = 0; ntl < 2; ++ntl) {
                int n = (w * 2 + ntl) * 16 + ln16;
                float4 lo = *(const float4*)(W2 + n * 256 + k);
                float4 hi = *(const float4*)(W2 + n * 256 + k + 4);
                half8 b;
                b[0] = (_Float16)lo.x; b[1] = (_Float16)lo.y;
                b[2] = (_Float16)lo.z; b[3] = (_Float16)lo.w;
                b[4] = (_Float16)hi.x; b[5] = (_Float16)hi.y;
                b[6] = (_Float16)hi.z; b[7] = (_Float16)hi.w;
                #pragma unroll
                for (int mt = 0; mt < 2; ++mt)
                    acc2[mt][ntl] = __builtin_amdgcn_mfma_f32_16x16x32_f16(
                        a[mt], b, acc2[mt][ntl], 0, 0, 0);
            }
        }
        #pragma unroll
        for (int mt = 0; mt < 2; ++mt)
            #pragma unroll
            for (int ntl = 0; ntl < 2; ++ntl) {
                int col = (w * 2 + ntl) * 16 + ln16;
                float bias = b2[col];
                #pragma unroll
                for (int reg = 0; reg < 4; ++reg) {
                    int row = mt * 16 + kq * 4 + reg;
                    h2[row * 132 + col] = fmaxf(acc2[mt][ntl][reg] + bias, 0.f);
                }
            }
    }
    __syncthreads();

    // MLP3: 128 -> 32 (scalar; small)
    {
        int c = t & 31;
        int g = t >> 5;
        int rb = g * 4;
        float acc[4];
        float bias = b3[c];
        #pragma unroll
        for (int r = 0; r < 4; ++r) acc[r] = bias;
        const float4* wrow = (const float4*)(W3 + c * 128);
        for (int k4 = 0; k4 < 32; ++k4) {
            float4 wv = wrow[k4];
            #pragma unroll
            for (int r = 0; r < 4; ++r) {
                const float4 hv = *(const float4*)(&h2[(rb + r) * 132 + k4 * 4]);
                acc[r] += wv.x * hv.x + wv.y * hv.y + wv.z * hv.z + wv.w * hv.w;
            }
        }
        #pragma unroll
        for (int r = 0; r < 4; ++r)
            out[(size_t)(r0 + rb + r) * 32 + c] = acc[r];
    }
}

extern "C" void kernel_launch(void* const* d_in, const int* in_sizes, int n_in,
                              void* d_out, int out_size, void* d_ws, size_t ws_size,
                              hipStream_t stream) {
    const float* x     = (const float*)d_in[0];
    const int*   adj   = (const int*)d_in[1];
    const float* Wg    = (const float*)d_in[2];
    const float* a     = (const float*)d_in[3];
    const float* gamma = (const float*)d_in[4];
    const float* beta  = (const float*)d_in[5];
    const float* W1    = (const float*)d_in[6];
    const float* b1    = (const float*)d_in[7];
    const float* W2    = (const float*)d_in[8];
    const float* b2    = (const float*)d_in[9];
    const float* W3    = (const float*)d_in[10];
    const float* b3    = (const float*)d_in[11];
    float* out = (float*)d_out;

    float* ws = (float*)d_ws;
    float* Wh       = ws;                          // 8192*48 f32
    float* s        = ws + (size_t)N * DH;         // 8192 f32
    _Float16* WhT16 = (_Float16*)(s + N);          // 64*8192 f16 (16B-aligned)
    float* accWs    = (float*)((char*)WhT16 + (size_t)64 * N * sizeof(_Float16));
                                                   // NSPLIT*8192*64 f32 = 33.5 MB

    k_wh<<<N * DH / 256, 256, 0, stream>>>(x, Wg, Wh);
    k_s<<<N / 256, 256, 0, stream>>>(Wh, a, s);
    k_tr<<<64 * N / 256, 256, 0, stream>>>(Wh, WhT16);
    k_gat<<<64 * NSPLIT, 256, 0, stream>>>(adj, WhT16, s, accWs);
    k_mlp<<<N / RB, 256, 0, stream>>>(accWs, gamma, beta, W1, b1, W2, b2, W3, b3, out);
}

// Round 5
// 453.079 us; speedup vs baseline: 1.0307x; 1.0071x over previous
//
#include <hip/hip_runtime.h>

#define N 8192
#define DIN 128
#define DH 48
#define MT 128           // rows per k_gat block (4 waves x 32 rows)
#define KC 64            // j-chunk
#define PSTR (KC + 8)    // f16 row stride: 144 B -> 2-way bank aliasing (free)
#define NSPLIT 16
#define JSPAN (N / NSPLIT)   // 512
#define NCHUNK (JSPAN / KC)  // 8
#define ACC_STRIDE 64    // 48 dims + lsum@48 + 15 unused (MFMA N-tile padding)
#define RB 32            // rows per k_mlp block

typedef _Float16 half8 __attribute__((ext_vector_type(8)));
typedef float f32x4 __attribute__((ext_vector_type(4)));

// ---------------- Kernel 1a: Wh = x @ Wgat^T  [8192,128]x[48,128] -> [8192,48]
__global__ __launch_bounds__(256) void k_wh(const float* __restrict__ x,
                                            const float* __restrict__ Wg,
                                            float* __restrict__ Wh) {
    __shared__ float wT[DIN * DH];  // transposed: wT[k*DH + c] = Wg[c*DIN + k]
    int t = threadIdx.x;
    for (int e = t; e < DIN * DH; e += 256) {
        int c = e / DIN, k = e % DIN;
        wT[k * DH + c] = Wg[e];
    }
    __syncthreads();
    int o = blockIdx.x * 256 + t;      // o < 8192*48
    int r = o / DH, c = o % DH;
    const float4* xr = (const float4*)(x + (size_t)r * DIN);
    float acc = 0.f;
    #pragma unroll 8
    for (int k4 = 0; k4 < DIN / 4; ++k4) {
        float4 xv = xr[k4];
        int kb = k4 * 4;
        acc += xv.x * wT[(kb + 0) * DH + c];
        acc += xv.y * wT[(kb + 1) * DH + c];
        acc += xv.z * wT[(kb + 2) * DH + c];
        acc += xv.w * wT[(kb + 3) * DH + c];
    }
    Wh[o] = acc;
}

// ---------------- Kernel 1b: s = Wh @ a^T
__global__ __launch_bounds__(256) void k_s(const float* __restrict__ Wh,
                                           const float* __restrict__ a,
                                           float* __restrict__ s) {
    int r = blockIdx.x * 256 + threadIdx.x;
    const float4* wr = (const float4*)(Wh + (size_t)r * DH);
    const float4* av = (const float4*)a;
    float acc = 0.f;
    #pragma unroll
    for (int k4 = 0; k4 < DH / 4; ++k4) {
        float4 w = wr[k4]; float4 aa = av[k4];
        acc += w.x * aa.x + w.y * aa.y + w.z * aa.z + w.w * aa.w;
    }
    s[r] = acc;
}

// ---------------- Kernel 1c: WhT16[d][j], d in [0,64):
//   d<48 : (f16)Wh[j][d]   (same RTN cast as old wS staging)
//   d=48 : 1.0  (ones column -> lsum)
//   d>48 : 0.0  (MFMA N-tile zero padding)
__global__ __launch_bounds__(256) void k_tr(const float* __restrict__ Wh,
                                            _Float16* __restrict__ WhT16) {
    int o = blockIdx.x * 256 + threadIdx.x;   // o < 64*8192, d-major
    int d = o >> 13, j = o & 8191;
    _Float16 v;
    if (d < DH)       v = (_Float16)Wh[(size_t)j * DH + d];
    else if (d == DH) v = (_Float16)1.0f;
    else              v = (_Float16)0.0f;
    WhT16[o] = v;
}

// ---------------- Kernel 2: fused masked-softmax attention, BARRIER-FREE,
// 4 blocks/CU. Each wave owns 32 rows end-to-end (private pS slice ->
// lgkmcnt only, no s_barrier, so the adj register prefetch stays in flight
// across the MFMA phase). Register diet for the 128-VGPR/4-block budget:
// B fragments split per K-half (bf0 issued before phase A -> oldest vmcnt
// slots; bf1 after the adj prefetch). Every wait leaves younger prefetches
// flying: bf0 -> [phase A] -> adjR' -> bf1 -> MFMA(bf0) -> MFMA(bf1).
// s-chunk (sj) prefetched with adjR. T5 setprio around the MFMA cluster
// (barrier-free waves sit at diverse phases -> scheduler has a choice).
__global__ __launch_bounds__(256, 4) void k_gat(const int* __restrict__ adj,
                                                const _Float16* __restrict__ WhT16,
                                                const float* __restrict__ s,
                                                float* __restrict__ accWs) {
    __shared__ _Float16 pS[MT][PSTR];   // A: P[row][j], per-wave 32-row slices
    __shared__ float sRow[MT];
    int t = threadIdx.x;
    int tile = blockIdx.x & 63;        // 64 row tiles of 128
    int split = blockIdx.x >> 6;       // 0..15
    int i0 = tile * MT;
    int jbase = split * JSPAN;

    int lane = t & 63, w = t >> 6;
    int ln16 = lane & 15, kq = lane >> 4;   // MFMA lane decomposition
    int jp = lane & 31, rh = lane >> 5;     // phase A: j-pair, row half

    int rw = w * 32;                        // wave's first row within tile
    const int* adjBase = adj + (size_t)(i0 + rw + rh * 16) * N + jbase + 2 * jp;

    // per-wave sRow staging (same-wave DS is in-order; lgkmcnt covers it)
    if (lane < 32) sRow[rw + lane] = s[i0 + rw + lane];

    // ---- prologue: chunk-0 prefetch (adj rows + s chunk) into registers
    int2 adjR[16];
    #pragma unroll
    for (int it = 0; it < 16; ++it)
        adjR[it] = *(const int2*)(adjBase + (size_t)it * N);
    float2 sjR = *(const float2*)(s + jbase + 2 * jp);

    f32x4 acc[2][4];
    #pragma unroll
    for (int a0 = 0; a0 < 2; ++a0)
        #pragma unroll
        for (int b0 = 0; b0 < 4; ++b0) acc[a0][b0] = (f32x4){0.f, 0.f, 0.f, 0.f};

    for (int chunk = 0; chunk < NCHUNK; ++chunk) {
        int j0 = jbase + chunk * KC;
        // ---- K-half-0 B fragments (oldest vmcnt slots; overlap phase A)
        half8 bf0[4];
        #pragma unroll
        for (int nt = 0; nt < 4; ++nt)
            bf0[nt] = *(const half8*)&WhT16[(size_t)(nt * 16 + ln16) * N
                                            + j0 + kq * 8];
        // ---- phase A: p (f16) for wave's 32 rows x 64 j from prefetched adjR
        {
            float2 sj = sjR;
            #pragma unroll
            for (int it = 0; it < 16; ++it) {
                int r = rw + rh * 16 + it;
                int2 av = adjR[it];
                float e0 = sRow[r] + sj.x;
                float e1 = sRow[r] + sj.y;
                e0 = fmaxf(e0, 0.2f * e0);              // LeakyReLU(0.2)
                e1 = fmaxf(e1, 0.2f * e1);
                float p0 = av.x ? __expf(e0) : 0.f;     // masked -> exact 0
                float p1 = av.y ? __expf(e1) : 0.f;
                union { _Float16 h[2]; unsigned u; } pk;
                pk.h[0] = (_Float16)p0;                 // RTN
                pk.h[1] = (_Float16)p1;
                *(unsigned*)&pS[r][2 * jp] = pk.u;
            }
        }
        // ---- issue next-chunk prefetch (no barrier ahead -> stays in flight)
        if (chunk < NCHUNK - 1) {
            #pragma unroll
            for (int it = 0; it < 16; ++it)
                adjR[it] = *(const int2*)(adjBase + (size_t)it * N + (chunk + 1) * KC);
            sjR = *(const float2*)(s + j0 + KC + 2 * jp);
        }
        // ---- K-half-1 B fragments (younger than adjR': waiting on these
        //      at the kt=1 MFMAs still leaves nothing older outstanding)
        half8 bf1[4];
        #pragma unroll
        for (int nt = 0; nt < 4; ++nt)
            bf1[nt] = *(const half8*)&WhT16[(size_t)(nt * 16 + ln16) * N
                                            + j0 + 32 + kq * 8];
        // ---- MFMA MAC (wave-internal pS: compiler inserts lgkmcnt, no barrier)
        __builtin_amdgcn_s_setprio(1);
        #pragma unroll
        for (int mtl = 0; mtl < 2; ++mtl) {
            half8 a = *(const half8*)&pS[rw + mtl * 16 + ln16][kq * 8];
            #pragma unroll
            for (int nt = 0; nt < 4; ++nt)
                acc[mtl][nt] = __builtin_amdgcn_mfma_f32_16x16x32_f16(
                    a, bf0[nt], acc[mtl][nt], 0, 0, 0);
        }
        #pragma unroll
        for (int mtl = 0; mtl < 2; ++mtl) {
            half8 a = *(const half8*)&pS[rw + mtl * 16 + ln16][32 + kq * 8];
            #pragma unroll
            for (int nt = 0; nt < 4; ++nt)
                acc[mtl][nt] = __builtin_amdgcn_mfma_f32_16x16x32_f16(
                    a, bf1[nt], acc[mtl][nt], 0, 0, 0);
        }
        __builtin_amdgcn_s_setprio(0);
    }
    // ---- epilogue: C/D layout col=lane&15, row=kq*4+reg
    size_t rbase = (size_t)split * N + i0;
    #pragma unroll
    for (int mtl = 0; mtl < 2; ++mtl) {
        #pragma unroll
        for (int nt = 0; nt < 4; ++nt) {
            int col = nt * 16 + ln16;
            if (nt == 3 && ln16 != 0) continue;   // only col 48 (lsum) useful
            #pragma unroll
            for (int reg = 0; reg < 4; ++reg) {
                int row = rw + mtl * 16 + kq * 4 + reg;
                accWs[(rbase + row) * ACC_STRIDE + col] = acc[mtl][nt][reg];
            }
        }
    }
}

// ---------------- Kernel 3: reduce splits + LayerNorm + MFMA MLP 48->256->128->32
__global__ __launch_bounds__(256) void k_mlp(const float* __restrict__ accWs,
                                             const float* __restrict__ gamma,
                                             const float* __restrict__ beta,
                                             const float* __restrict__ W1, const float* __restrict__ b1,
                                             const float* __restrict__ W2, const float* __restrict__ b2,
                                             const float* __restrict__ W3, const float* __restrict__ b3,
                                             float* __restrict__ out) {
    __shared__ float hacc[RB * 49];
    __shared__ _Float16 hN[RB * 72];    // [32][72] f16, cols 48..71 zero (K pad)
    __shared__ _Float16 h1[RB * 264];   // [32][264] f16
    __shared__ float h2[RB * 132];      // [32][132] f32
    int t = threadIdx.x;
    int r0 = blockIdx.x * RB;
    int lane = t & 63, w = t >> 6;
    int ln16 = lane & 15, kq = lane >> 4;

    // reduce K-split partials (d: 0..47 dims, 48 = lsum)
    for (int e = t; e < RB * 49; e += 256) {
        int r = e / 49, d = e % 49;
        size_t base = (size_t)(r0 + r) * ACC_STRIDE + d;
        float v = 0.f;
        #pragma unroll
        for (int sp = 0; sp < NSPLIT; ++sp)
            v += accWs[(size_t)sp * N * ACC_STRIDE + base];
        hacc[e] = v;
    }
    __syncthreads();

    // LayerNorm (two-pass), h' = acc / l ; store f16 for MFMA A-operand
    if (t < RB) {
        float invl = 1.f / hacc[t * 49 + 48];
        float sum = 0.f;
        for (int d = 0; d < DH; ++d) sum += hacc[t * 49 + d];
        float mean = sum * invl * (1.f / DH);
        float var = 0.f;
        for (int d = 0; d < DH; ++d) {
            float dv = hacc[t * 49 + d] * invl - mean;
            var += dv * dv;
        }
        var *= (1.f / DH);
        float rs = rsqrtf(var + 1e-5f);
        for (int d = 0; d < DH; ++d) {
            float hv = (hacc[t * 49 + d] * invl - mean) * rs;
            hN[t * 72 + d] = (_Float16)(hv * gamma[d] + beta[d]);
        }
        for (int d = DH; d < 72; ++d) hN[t * 72 + d] = (_Float16)0.f;
    }
    __syncthreads();

    // MLP1 (MFMA): M=32, N=256, K=48 padded to 64. wave w owns N-tiles w*4..w*4+3
    {
        f32x4 acc1[2][4];
        #pragma unroll
        for (int mt = 0; mt < 2; ++mt)
            #pragma unroll
            for (int nt = 0; nt < 4; ++nt) acc1[mt][nt] = (f32x4){0.f, 0.f, 0.f, 0.f};
        #pragma unroll
        for (int kt = 0; kt < 2; ++kt) {
            int k = kt * 32 + kq * 8;
            half8 a[2];
            #pragma unroll
            for (int mt = 0; mt < 2; ++mt)
                a[mt] = *(const half8*)&hN[(mt * 16 + ln16) * 72 + k];
            #pragma unroll
            for (int ntl = 0; ntl < 4; ++ntl) {
                int n = (w * 4 + ntl) * 16 + ln16;
                half8 b;
                #pragma unroll
                for (int i = 0; i < 8; ++i) b[i] = (_Float16)0.f;
                if (k < DH) {   // k in {0,8,16,24,32,40}; >=48 stays zero
                    float4 lo = *(const float4*)(W1 + n * DH + k);
                    float4 hi = *(const float4*)(W1 + n * DH + k + 4);
                    b[0] = (_Float16)lo.x; b[1] = (_Float16)lo.y;
                    b[2] = (_Float16)lo.z; b[3] = (_Float16)lo.w;
                    b[4] = (_Float16)hi.x; b[5] = (_Float16)hi.y;
                    b[6] = (_Float16)hi.z; b[7] = (_Float16)hi.w;
                }
                #pragma unroll
                for (int mt = 0; mt < 2; ++mt)
                    acc1[mt][ntl] = __builtin_amdgcn_mfma_f32_16x16x32_f16(
                        a[mt], b, acc1[mt][ntl], 0, 0, 0);
            }
        }
        #pragma unroll
        for (int mt = 0; mt < 2; ++mt)
            #pragma unroll
            for (int ntl = 0; ntl < 4; ++ntl) {
                int col = (w * 4 + ntl) * 16 + ln16;
                float bias = b1[col];
                #pragma unroll
                for (int reg = 0; reg < 4; ++reg) {
                    int row = mt * 16 + kq * 4 + reg;
                    float v = acc1[mt][ntl][reg] + bias;
                    h1[row * 264 + col] = (_Float16)fmaxf(v, 0.f);
                }
            }
    }
    __syncthreads();

    // MLP2 (MFMA): M=32, N=128, K=256. wave w owns N-tiles w*2, w*2+1
    {
        f32x4 acc2[2][2];
        #pragma unroll
        for (int mt = 0; mt < 2; ++mt)
            #pragma unroll
            for (int nt = 0; nt < 2; ++nt) acc2[mt][nt] = (f32x4){0.f, 0.f, 0.f, 0.f};
        #pragma unroll
        for (int kt = 0; kt < 8; ++kt) {
            int k = kt * 32 + kq * 8;
            half8 a[2];
            #pragma unroll
            for (int mt = 0; mt < 2; ++mt)
                a[mt] = *(const half8*)&h1[(mt * 16 + ln16) * 264 + k];
            #pragma unroll
            for (int ntl = 0; ntl < 2; ++ntl) {
                int n = (w * 2 + ntl) * 16 + ln16;
                float4 lo = *(const float4*)(W2 + n * 256 + k);
                float4 hi = *(const float4*)(W2 + n * 256 + k + 4);
                half8 b;
                b[0] = (_Float16)lo.x; b[1] = (_Float16)lo.y;
                b[2] = (_Float16)lo.z; b[3] = (_Float16)lo.w;
                b[4] = (_Float16)hi.x; b[5] = (_Float16)hi.y;
                b[6] = (_Float16)hi.z; b[7] = (_Float16)hi.w;
                #pragma unroll
                for (int mt = 0; mt < 2; ++mt)
                    acc2[mt][ntl] = __builtin_amdgcn_mfma_f32_16x16x32_f16(
                        a[mt], b, acc2[mt][ntl], 0, 0, 0);
            }
        }
        #pragma unroll
        for (int mt = 0; mt < 2; ++mt)
            #pragma unroll
            for (int ntl = 0; ntl < 2; ++ntl) {
                int col = (w * 2 + ntl) * 16 + ln16;
                float bias = b2[col];
                #pragma unroll
                for (int reg = 0; reg < 4; ++reg) {
                    int row = mt * 16 + kq * 4 + reg;
                    h2[row * 132 + col] = fmaxf(acc2[mt][ntl][reg] + bias, 0.f);
                }
            }
    }
    __syncthreads();

    // MLP3: 128 -> 32 (scalar; small)
    {
        int c = t & 31;
        int g = t >> 5;
        int rb = g * 4;
        float acc[4];
        float bias = b3[c];
        #pragma unroll
        for (int r = 0; r < 4; ++r) acc[r] = bias;
        const float4* wrow = (const float4*)(W3 + c * 128);
        for (int k4 = 0; k4 < 32; ++k4) {
            float4 wv = wrow[k4];
            #pragma unroll
            for (int r = 0; r < 4; ++r) {
                const float4 hv = *(const float4*)(&h2[(rb + r) * 132 + k4 * 4]);
                acc[r] += wv.x * hv.x + wv.y * hv.y + wv.z * hv.z + wv.w * hv.w;
            }
        }
        #pragma unroll
        for (int r = 0; r < 4; ++r)
            out[(size_t)(r0 + rb + r) * 32 + c] = acc[r];
    }
}

extern "C" void kernel_launch(void* const* d_in, const int* in_sizes, int n_in,
                              void* d_out, int out_size, void* d_ws, size_t ws_size,
                              hipStream_t stream) {
    const float* x     = (const float*)d_in[0];
    const int*   adj   = (const int*)d_in[1];
    const float* Wg    = (const float*)d_in[2];
    const float* a     = (const float*)d_in[3];
    const float* gamma = (const float*)d_in[4];
    const float* beta  = (const float*)d_in[5];
    const float* W1    = (const float*)d_in[6];
    const float* b1    = (const float*)d_in[7];
    const float* W2    = (const float*)d_in[8];
    const float* b2    = (const float*)d_in[9];
    const float* W3    = (const float*)d_in[10];
    const float* b3    = (const float*)d_in[11];
    float* out = (float*)d_out;

    float* ws = (float*)d_ws;
    float* Wh       = ws;                          // 8192*48 f32
    float* s        = ws + (size_t)N * DH;         // 8192 f32
    _Float16* WhT16 = (_Float16*)(s + N);          // 64*8192 f16 (16B-aligned)
    float* accWs    = (float*)((char*)WhT16 + (size_t)64 * N * sizeof(_Float16));
                                                   // NSPLIT*8192*64 f32 = 33.5 MB

    k_wh<<<N * DH / 256, 256, 0, stream>>>(x, Wg, Wh);
    k_s<<<N / 256, 256, 0, stream>>>(Wh, a, s);
    k_tr<<<64 * N / 256, 256, 0, stream>>>(Wh, WhT16);
    k_gat<<<64 * NSPLIT, 256, 0, stream>>>(adj, WhT16, s, accWs);
    k_mlp<<<N / RB, 256, 0, stream>>>(accWs, gamma, beta, W1, b1, W2, b2, W3, b3, out);
}

// Round 6
// 434.958 us; speedup vs baseline: 1.0737x; 1.0417x over previous
//
#include <hip/hip_runtime.h>

#define N 8192
#define DIN 128
#define DH 48
#define MT 128           // rows per k_gat block (4 waves x 32 rows)
#define KC 64            // j-chunk
#define PSTR (KC + 8)    // f16 row stride: 144 B -> 2-way bank aliasing (free)
#define NSPLIT 16
#define JSPAN (N / NSPLIT)   // 512
#define NCHUNK (JSPAN / KC)  // 8
#define ACC_STRIDE 64    // 48 dims + lsum@48 + 15 unused (MFMA N-tile padding)
#define RB 32            // rows per k_mlp block

typedef _Float16 half8 __attribute__((ext_vector_type(8)));
typedef float f32x4 __attribute__((ext_vector_type(4)));

// ---------------- Kernel 1a: Wh = x @ Wgat^T  [8192,128]x[48,128] -> [8192,48]
__global__ __launch_bounds__(256) void k_wh(const float* __restrict__ x,
                                            const float* __restrict__ Wg,
                                            float* __restrict__ Wh) {
    __shared__ float wT[DIN * DH];  // transposed: wT[k*DH + c] = Wg[c*DIN + k]
    int t = threadIdx.x;
    for (int e = t; e < DIN * DH; e += 256) {
        int c = e / DIN, k = e % DIN;
        wT[k * DH + c] = Wg[e];
    }
    __syncthreads();
    int o = blockIdx.x * 256 + t;      // o < 8192*48
    int r = o / DH, c = o % DH;
    const float4* xr = (const float4*)(x + (size_t)r * DIN);
    float acc = 0.f;
    #pragma unroll 8
    for (int k4 = 0; k4 < DIN / 4; ++k4) {
        float4 xv = xr[k4];
        int kb = k4 * 4;
        acc += xv.x * wT[(kb + 0) * DH + c];
        acc += xv.y * wT[(kb + 1) * DH + c];
        acc += xv.z * wT[(kb + 2) * DH + c];
        acc += xv.w * wT[(kb + 3) * DH + c];
    }
    Wh[o] = acc;
}

// ---------------- Kernel 1b: s = Wh @ a^T
__global__ __launch_bounds__(256) void k_s(const float* __restrict__ Wh,
                                           const float* __restrict__ a,
                                           float* __restrict__ s) {
    int r = blockIdx.x * 256 + threadIdx.x;
    const float4* wr = (const float4*)(Wh + (size_t)r * DH);
    const float4* av = (const float4*)a;
    float acc = 0.f;
    #pragma unroll
    for (int k4 = 0; k4 < DH / 4; ++k4) {
        float4 w = wr[k4]; float4 aa = av[k4];
        acc += w.x * aa.x + w.y * aa.y + w.z * aa.z + w.w * aa.w;
    }
    s[r] = acc;
}

// ---------------- Kernel 1c: WhT16[d][j], d in [0,64):
//   d<48 : (f16)Wh[j][d]   (same RTN cast as old wS staging)
//   d=48 : 1.0  (ones column -> lsum)
//   d>48 : 0.0  (MFMA N-tile zero padding)
__global__ __launch_bounds__(256) void k_tr(const float* __restrict__ Wh,
                                            _Float16* __restrict__ WhT16) {
    int o = blockIdx.x * 256 + threadIdx.x;   // o < 64*8192, d-major
    int d = o >> 13, j = o & 8191;
    _Float16 v;
    if (d < DH)       v = (_Float16)Wh[(size_t)j * DH + d];
    else if (d == DH) v = (_Float16)1.0f;
    else              v = (_Float16)0.0f;
    WhT16[o] = v;
}

// ---------------- Kernel 2: fused masked-softmax attention, BARRIER-FREE,
// with per-wave CHUNK ROTATION for HBM channel/page diversity.
//
// Diagnosis (R1/R4/R5): k_gat pinned at ~1.9 TB/s (30% of achievable) with
// all pipes idle -- concurrent waves of a split all read the SAME 256-B
// j-column window at a 32-KB row stride, so the instantaneous request
// stream covers only a slice of the HBM channel/bank interleave (addr bits
// [8:12]) and thrashes DRAM pages (256 B used per page open). Fix: rotate
// each wave's chunk order by (tile + 2*w) & 7 so resident waves read all 8
// column phases simultaneously. Accumulation over chunks is commutative.
//
// Load order per chunk (restores R4's pipeline; R5 had bf1 younger than the
// adjR' prefetch, forcing vmcnt(0) at the MFMA): bf[2][4] first (oldest),
// phase A consumes adjR, THEN adjR'/sj' prefetch issued and pinned with a
// sched_barrier so the scheduler cannot sink it to its use; the MFMA waits
// on bf at vmcnt(16), leaving the prefetch in flight.
__global__ __launch_bounds__(256, 3) void k_gat(const int* __restrict__ adj,
                                                const _Float16* __restrict__ WhT16,
                                                const float* __restrict__ s,
                                                float* __restrict__ accWs) {
    __shared__ _Float16 pS[MT][PSTR];   // A: P[row][j], per-wave 32-row slices
    __shared__ float sRow[MT];
    int t = threadIdx.x;
    int tile = blockIdx.x & 63;        // 64 row tiles of 128
    int split = blockIdx.x >> 6;       // 0..15
    int i0 = tile * MT;
    int jbase = split * JSPAN;

    int lane = t & 63, w = t >> 6;
    int ln16 = lane & 15, kq = lane >> 4;   // MFMA lane decomposition
    int jp = lane & 31, rh = lane >> 5;     // phase A: j-pair, row half

    int rw = w * 32;                        // wave's first row within tile
    int phase = (tile + 2 * w) & (NCHUNK - 1);   // per-wave chunk rotation
    const int* adjBase = adj + (size_t)(i0 + rw + rh * 16) * N + jbase + 2 * jp;

    // per-wave sRow staging (same-wave DS is in-order; lgkmcnt covers it)
    if (lane < 32) sRow[rw + lane] = s[i0 + rw + lane];

    // ---- prologue: first-chunk prefetch (adj rows + s chunk) into registers
    int chunk0 = phase;
    int2 adjR[16];
    #pragma unroll
    for (int it = 0; it < 16; ++it)
        adjR[it] = *(const int2*)(adjBase + (size_t)it * N + chunk0 * KC);
    float2 sjR = *(const float2*)(s + jbase + chunk0 * KC + 2 * jp);

    f32x4 acc[2][4];
    #pragma unroll
    for (int a0 = 0; a0 < 2; ++a0)
        #pragma unroll
        for (int b0 = 0; b0 < 4; ++b0) acc[a0][b0] = (f32x4){0.f, 0.f, 0.f, 0.f};

    for (int cc = 0; cc < NCHUNK; ++cc) {
        int chunk = (cc + phase) & (NCHUNK - 1);
        int j0 = jbase + chunk * KC;
        // ---- B fragments for this chunk (oldest vmcnt slots: the MFMA's
        //      wait on these leaves the younger adjR' prefetch in flight)
        half8 bf[2][4];
        #pragma unroll
        for (int kt = 0; kt < 2; ++kt)
            #pragma unroll
            for (int nt = 0; nt < 4; ++nt)
                bf[kt][nt] = *(const half8*)&WhT16[(size_t)(nt * 16 + ln16) * N
                                                  + j0 + kt * 32 + kq * 8];
        // ---- phase A: p (f16) for wave's 32 rows x 64 j from prefetched adjR
        {
            float2 sj = sjR;
            #pragma unroll
            for (int it = 0; it < 16; ++it) {
                int r = rw + rh * 16 + it;
                int2 av = adjR[it];
                float e0 = sRow[r] + sj.x;
                float e1 = sRow[r] + sj.y;
                e0 = fmaxf(e0, 0.2f * e0);              // LeakyReLU(0.2)
                e1 = fmaxf(e1, 0.2f * e1);
                float p0 = av.x ? __expf(e0) : 0.f;     // masked -> exact 0
                float p1 = av.y ? __expf(e1) : 0.f;
                union { _Float16 h[2]; unsigned u; } pk;
                pk.h[0] = (_Float16)p0;                 // RTN
                pk.h[1] = (_Float16)p1;
                *(unsigned*)&pS[r][2 * jp] = pk.u;
            }
        }
        // ---- issue next-chunk prefetch; sched_barrier pins the issue point
        //      so the scheduler cannot sink these loads down to their use
        if (cc < NCHUNK - 1) {
            int nchunk = (cc + 1 + phase) & (NCHUNK - 1);
            #pragma unroll
            for (int it = 0; it < 16; ++it)
                adjR[it] = *(const int2*)(adjBase + (size_t)it * N + nchunk * KC);
            sjR = *(const float2*)(s + jbase + nchunk * KC + 2 * jp);
        }
        __builtin_amdgcn_sched_barrier(0);
        // ---- MFMA MAC (wave-internal pS: compiler inserts lgkmcnt, no barrier)
        __builtin_amdgcn_s_setprio(1);
        #pragma unroll
        for (int kt = 0; kt < 2; ++kt) {
            const int kk = kt * 32 + kq * 8;
            #pragma unroll
            for (int mtl = 0; mtl < 2; ++mtl) {
                half8 a = *(const half8*)&pS[rw + mtl * 16 + ln16][kk];
                #pragma unroll
                for (int nt = 0; nt < 4; ++nt)
                    acc[mtl][nt] = __builtin_amdgcn_mfma_f32_16x16x32_f16(
                        a, bf[kt][nt], acc[mtl][nt], 0, 0, 0);
            }
        }
        __builtin_amdgcn_s_setprio(0);
    }
    // ---- epilogue: C/D layout col=lane&15, row=kq*4+reg
    size_t rbase = (size_t)split * N + i0;
    #pragma unroll
    for (int mtl = 0; mtl < 2; ++mtl) {
        #pragma unroll
        for (int nt = 0; nt < 4; ++nt) {
            int col = nt * 16 + ln16;
            if (nt == 3 && ln16 != 0) continue;   // only col 48 (lsum) useful
            #pragma unroll
            for (int reg = 0; reg < 4; ++reg) {
                int row = rw + mtl * 16 + kq * 4 + reg;
                accWs[(rbase + row) * ACC_STRIDE + col] = acc[mtl][nt][reg];
            }
        }
    }
}

// ---------------- Kernel 3: reduce splits + LayerNorm + MFMA MLP 48->256->128->32
__global__ __launch_bounds__(256) void k_mlp(const float* __restrict__ accWs,
                                             const float* __restrict__ gamma,
                                             const float* __restrict__ beta,
                                             const float* __restrict__ W1, const float* __restrict__ b1,
                                             const float* __restrict__ W2, const float* __restrict__ b2,
                                             const float* __restrict__ W3, const float* __restrict__ b3,
                                             float* __restrict__ out) {
    __shared__ float hacc[RB * 49];
    __shared__ _Float16 hN[RB * 72];    // [32][72] f16, cols 48..71 zero (K pad)
    __shared__ _Float16 h1[RB * 264];   // [32][264] f16
    __shared__ float h2[RB * 132];      // [32][132] f32
    int t = threadIdx.x;
    int r0 = blockIdx.x * RB;
    int lane = t & 63, w = t >> 6;
    int ln16 = lane & 15, kq = lane >> 4;

    // reduce K-split partials (d: 0..47 dims, 48 = lsum)
    for (int e = t; e < RB * 49; e += 256) {
        int r = e / 49, d = e % 49;
        size_t base = (size_t)(r0 + r) * ACC_STRIDE + d;
        float v = 0.f;
        #pragma unroll
        for (int sp = 0; sp < NSPLIT; ++sp)
            v += accWs[(size_t)sp * N * ACC_STRIDE + base];
        hacc[e] = v;
    }
    __syncthreads();

    // LayerNorm (two-pass), h' = acc / l ; store f16 for MFMA A-operand
    if (t < RB) {
        float invl = 1.f / hacc[t * 49 + 48];
        float sum = 0.f;
        for (int d = 0; d < DH; ++d) sum += hacc[t * 49 + d];
        float mean = sum * invl * (1.f / DH);
        float var = 0.f;
        for (int d = 0; d < DH; ++d) {
            float dv = hacc[t * 49 + d] * invl - mean;
            var += dv * dv;
        }
        var *= (1.f / DH);
        float rs = rsqrtf(var + 1e-5f);
        for (int d = 0; d < DH; ++d) {
            float hv = (hacc[t * 49 + d] * invl - mean) * rs;
            hN[t * 72 + d] = (_Float16)(hv * gamma[d] + beta[d]);
        }
        for (int d = DH; d < 72; ++d) hN[t * 72 + d] = (_Float16)0.f;
    }
    __syncthreads();

    // MLP1 (MFMA): M=32, N=256, K=48 padded to 64. wave w owns N-tiles w*4..w*4+3
    {
        f32x4 acc1[2][4];
        #pragma unroll
        for (int mt = 0; mt < 2; ++mt)
            #pragma unroll
            for (int nt = 0; nt < 4; ++nt) acc1[mt][nt] = (f32x4){0.f, 0.f, 0.f, 0.f};
        #pragma unroll
        for (int kt = 0; kt < 2; ++kt) {
            int k = kt * 32 + kq * 8;
            half8 a[2];
            #pragma unroll
            for (int mt = 0; mt < 2; ++mt)
                a[mt] = *(const half8*)&hN[(mt * 16 + ln16) * 72 + k];
            #pragma unroll
            for (int ntl = 0; ntl < 4; ++ntl) {
                int n = (w * 4 + ntl) * 16 + ln16;
                half8 b;
                #pragma unroll
                for (int i = 0; i < 8; ++i) b[i] = (_Float16)0.f;
                if (k < DH) {   // k in {0,8,16,24,32,40}; >=48 stays zero
                    float4 lo = *(const float4*)(W1 + n * DH + k);
                    float4 hi = *(const float4*)(W1 + n * DH + k + 4);
                    b[0] = (_Float16)lo.x; b[1] = (_Float16)lo.y;
                    b[2] = (_Float16)lo.z; b[3] = (_Float16)lo.w;
                    b[4] = (_Float16)hi.x; b[5] = (_Float16)hi.y;
                    b[6] = (_Float16)hi.z; b[7] = (_Float16)hi.w;
                }
                #pragma unroll
                for (int mt = 0; mt < 2; ++mt)
                    acc1[mt][ntl] = __builtin_amdgcn_mfma_f32_16x16x32_f16(
                        a[mt], b, acc1[mt][ntl], 0, 0, 0);
            }
        }
        #pragma unroll
        for (int mt = 0; mt < 2; ++mt)
            #pragma unroll
            for (int ntl = 0; ntl < 4; ++ntl) {
                int col = (w * 4 + ntl) * 16 + ln16;
                float bias = b1[col];
                #pragma unroll
                for (int reg = 0; reg < 4; ++reg) {
                    int row = mt * 16 + kq * 4 + reg;
                    float v = acc1[mt][ntl][reg] + bias;
                    h1[row * 264 + col] = (_Float16)fmaxf(v, 0.f);
                }
            }
    }
    __syncthreads();

    // MLP2 (MFMA): M=32, N=128, K=256. wave w owns N-tiles w*2, w*2+1
    {
        f32x4 acc2[2][2];
        #pragma unroll
        for (int mt = 0; mt < 2; ++mt)
            #pragma unroll
            for (int nt = 0; nt < 2; ++nt) acc2[mt][nt] = (f32x4){0.f, 0.f, 0.f, 0.f};
        #pragma unroll
        for (int kt = 0; kt < 8; ++kt) {
            int k = kt * 32 + kq * 8;
            half8 a[2];
            #pragma unroll
            for (int mt = 0; mt < 2; ++mt)
                a[mt] = *(const half8*)&h1[(mt * 16 + ln16) * 264 + k];
            #pragma unroll
            for (int ntl = 0; ntl < 2; ++ntl) {
                int n = (w * 2 + ntl) * 16 + ln16;
                float4 lo = *(const float4*)(W2 + n * 256 + k);
                float4 hi = *(const float4*)(W2 + n * 256 + k + 4);
                half8 b;
                b[0] = (_Float16)lo.x; b[1] = (_Float16)lo.y;
                b[2] = (_Float16)lo.z; b[3] = (_Float16)lo.w;
                b[4] = (_Float16)hi.x; b[5] = (_Float16)hi.y;
                b[6] = (_Float16)hi.z; b[7] = (_Float16)hi.w;
                #pragma unroll
                for (int mt = 0; mt < 2; ++mt)
                    acc2[mt][ntl] = __builtin_amdgcn_mfma_f32_16x16x32_f16(
                        a[mt], b, acc2[mt][ntl], 0, 0, 0);
            }
        }
        #pragma unroll
        for (int mt = 0; mt < 2; ++mt)
            #pragma unroll
            for (int ntl = 0; ntl < 2; ++ntl) {
                int col = (w * 2 + ntl) * 16 + ln16;
                float bias = b2[col];
                #pragma unroll
                for (int reg = 0; reg < 4; ++reg) {
                    int row = mt * 16 + kq * 4 + reg;
                    h2[row * 132 + col] = fmaxf(acc2[mt][ntl][reg] + bias, 0.f);
                }
            }
    }
    __syncthreads();

    // MLP3: 128 -> 32 (scalar; small)
    {
        int c = t & 31;
        int g = t >> 5;
        int rb = g * 4;
        float acc[4];
        float bias = b3[c];
        #pragma unroll
        for (int r = 0; r < 4; ++r) acc[r] = bias;
        const float4* wrow = (const float4*)(W3 + c * 128);
        for (int k4 = 0; k4 < 32; ++k4) {
            float4 wv = wrow[k4];
            #pragma unroll
            for (int r = 0; r < 4; ++r) {
                const float4 hv = *(const float4*)(&h2[(rb + r) * 132 + k4 * 4]);
                acc[r] += wv.x * hv.x + wv.y * hv.y + wv.z * hv.z + wv.w * hv.w;
            }
        }
        #pragma unroll
        for (int r = 0; r < 4; ++r)
            out[(size_t)(r0 + rb + r) * 32 + c] = acc[r];
    }
}

extern "C" void kernel_launch(void* const* d_in, const int* in_sizes, int n_in,
                              void* d_out, int out_size, void* d_ws, size_t ws_size,
                              hipStream_t stream) {
    const float* x     = (const float*)d_in[0];
    const int*   adj   = (const int*)d_in[1];
    const float* Wg    = (const float*)d_in[2];
    const float* a     = (const float*)d_in[3];
    const float* gamma = (const float*)d_in[4];
    const float* beta  = (const float*)d_in[5];
    const float* W1    = (const float*)d_in[6];
    const float* b1    = (const float*)d_in[7];
    const float* W2    = (const float*)d_in[8];
    const float* b2    = (const float*)d_in[9];
    const float* W3    = (const float*)d_in[10];
    const float* b3    = (const float*)d_in[11];
    float* out = (float*)d_out;

    float* ws = (float*)d_ws;
    float* Wh       = ws;                          // 8192*48 f32
    float* s        = ws + (size_t)N * DH;         // 8192 f32
    _Float16* WhT16 = (_Float16*)(s + N);          // 64*8192 f16 (16B-aligned)
    float* accWs    = (float*)((char*)WhT16 + (size_t)64 * N * sizeof(_Float16));
                                                   // NSPLIT*8192*64 f32 = 33.5 MB

    k_wh<<<N * DH / 256, 256, 0, stream>>>(x, Wg, Wh);
    k_s<<<N / 256, 256, 0, stream>>>(Wh, a, s);
    k_tr<<<64 * N / 256, 256, 0, stream>>>(Wh, WhT16);
    k_gat<<<64 * NSPLIT, 256, 0, stream>>>(adj, WhT16, s, accWs);
    k_mlp<<<N / RB, 256, 0, stream>>>(accWs, gamma, beta, W1, b1, W2, b2, W3, b3, out);
}